// Round 1
// baseline (823.285 us; speedup 1.0000x reference)
//
#include <hip/hip_runtime.h>
#include <math.h>

#define BB 32
#define LL 2048
#define DD 64
#define UU 40
#define NEG_BIG (-3.0e38f)

// ---------------------------------------------------------------------------
// Kernel 1: Ksum[b][d] = sum_j K[b, idx[j], d]   (duplicates counted, U_part=L)
// ---------------------------------------------------------------------------
__global__ __launch_bounds__(256) void ksum_kernel(const float* __restrict__ K,
                                                   const int* __restrict__ idx,
                                                   float* __restrict__ Ksum) {
  int b = blockIdx.x;
  int tid = threadIdx.x;
  int d = tid & 63;
  int c = tid >> 6;  // 0..3
  const float* Kb = K + (size_t)b * LL * DD;
  float acc = 0.f;
  int j0 = c * (LL / 4), j1 = j0 + (LL / 4);
  for (int j = j0; j < j1; ++j) {
    acc += Kb[(size_t)idx[j] * DD + d];  // threads d=0..63 coalesced per j
  }
  __shared__ float red[256];
  red[tid] = acc;
  __syncthreads();
  if (c == 0) Ksum[b * DD + d] = red[d] + red[64 + d] + red[128 + d] + red[192 + d];
}

// ---------------------------------------------------------------------------
// Kernel 2: M[b][q] = max_j (Q[b,q]·K[b,idx[j]]) - (Q[b,q]·Ksum[b]) / L
// Block = 256 thr, tile 64 queries; loop 32 chunks of 64 sampled keys.
// Thread (tx=tid&15, ty=tid>>4) computes 4q x 4k dots; LDS layouts are
// transposed ([d][q], [d][k]) so inner loop is 2x ds_read_b128 + 16 FMA.
// ---------------------------------------------------------------------------
__global__ __launch_bounds__(256) void m_kernel(const float* __restrict__ Q,
                                                const float* __restrict__ K,
                                                const int* __restrict__ idx,
                                                const float* __restrict__ Ksum,
                                                float* __restrict__ M) {
  __shared__ float Qs[64][64];    // [d][q]
  __shared__ float Ks[64][64];    // [d][k]
  __shared__ float KsumS[64];
  __shared__ float red[64][17];   // [q][ty], padded

  int b = blockIdx.y;
  int q0 = blockIdx.x * 64;
  int tid = threadIdx.x;
  int tx = tid & 15;   // query group
  int ty = tid >> 4;   // key group

  if (tid < 64) KsumS[tid] = Ksum[b * DD + tid];

  // stage Q tile, transposed
  for (int it = 0; it < 4; ++it) {
    int li = it * 256 + tid;      // 0..1023
    int q = li >> 4;
    int dd = (li & 15) << 2;
    const float4 v = *(const float4*)(Q + ((size_t)b * LL + q0 + q) * DD + dd);
    Qs[dd + 0][q] = v.x; Qs[dd + 1][q] = v.y; Qs[dd + 2][q] = v.z; Qs[dd + 3][q] = v.w;
  }

  float mx[4] = {NEG_BIG, NEG_BIG, NEG_BIG, NEG_BIG};

  for (int c = 0; c < LL / 64; ++c) {
    __syncthreads();  // protect Ks from previous iteration's readers
    // stage gathered K chunk, transposed
    for (int it = 0; it < 4; ++it) {
      int li = it * 256 + tid;
      int kk = li >> 4;
      int dd = (li & 15) << 2;
      int gk = idx[c * 64 + kk];
      const float4 v = *(const float4*)(K + ((size_t)b * LL + gk) * DD + dd);
      Ks[dd + 0][kk] = v.x; Ks[dd + 1][kk] = v.y; Ks[dd + 2][kk] = v.z; Ks[dd + 3][kk] = v.w;
    }
    __syncthreads();

    float acc[4][4];
#pragma unroll
    for (int i = 0; i < 4; ++i)
#pragma unroll
      for (int j = 0; j < 4; ++j) acc[i][j] = 0.f;

#pragma unroll 16
    for (int d = 0; d < 64; ++d) {
      float4 qv = *(const float4*)&Qs[d][tx << 2];
      float4 kv = *(const float4*)&Ks[d][ty << 2];
      acc[0][0] += qv.x * kv.x; acc[0][1] += qv.x * kv.y; acc[0][2] += qv.x * kv.z; acc[0][3] += qv.x * kv.w;
      acc[1][0] += qv.y * kv.x; acc[1][1] += qv.y * kv.y; acc[1][2] += qv.y * kv.z; acc[1][3] += qv.y * kv.w;
      acc[2][0] += qv.z * kv.x; acc[2][1] += qv.z * kv.y; acc[2][2] += qv.z * kv.z; acc[2][3] += qv.z * kv.w;
      acc[3][0] += qv.w * kv.x; acc[3][1] += qv.w * kv.y; acc[3][2] += qv.w * kv.z; acc[3][3] += qv.w * kv.w;
    }
#pragma unroll
    for (int i = 0; i < 4; ++i) {
      float m = fmaxf(fmaxf(acc[i][0], acc[i][1]), fmaxf(acc[i][2], acc[i][3]));
      mx[i] = fmaxf(mx[i], m);
    }
  }

  __syncthreads();
#pragma unroll
  for (int i = 0; i < 4; ++i) red[(tx << 2) + i][ty] = mx[i];
  __syncthreads();

  if (tid < 64) {
    int q = tid;
    float m = red[q][0];
#pragma unroll
    for (int t = 1; t < 16; ++t) m = fmaxf(m, red[q][t]);
    float s = 0.f;
#pragma unroll 16
    for (int d = 0; d < 64; ++d) s += Qs[d][q] * KsumS[d];
    M[b * LL + q0 + q] = m - s * (1.0f / (float)LL);
  }
}

// ---------------------------------------------------------------------------
// Kernel 3: per-batch top-40 of M, exact lax.top_k order (desc, ties->low idx)
// ---------------------------------------------------------------------------
__global__ __launch_bounds__(256) void topk_kernel(const float* __restrict__ M,
                                                   int* __restrict__ topi) {
  int b = blockIdx.x;
  int tid = threadIdx.x;
  __shared__ float mv[LL];
  __shared__ float rv[256];
  __shared__ int ri[256];
  for (int j = tid; j < LL; j += 256) mv[j] = M[b * LL + j];
  __syncthreads();
  for (int t = 0; t < UU; ++t) {
    float bv = NEG_BIG; int bi = LL;
    for (int j = tid; j < LL; j += 256) {
      float v = mv[j];
      if (v > bv) { bv = v; bi = j; }  // ascending scan: keeps lowest index on ties
    }
    rv[tid] = bv; ri[tid] = bi;
    __syncthreads();
    for (int s = 128; s > 0; s >>= 1) {
      if (tid < s) {
        if (rv[tid + s] > rv[tid] || (rv[tid + s] == rv[tid] && ri[tid + s] < ri[tid])) {
          rv[tid] = rv[tid + s]; ri[tid] = ri[tid + s];
        }
      }
      __syncthreads();
    }
    if (tid == 0) { topi[b * UU + t] = ri[0]; mv[ri[0]] = NEG_BIG; }
    __syncthreads();
  }
}

// ---------------------------------------------------------------------------
// Kernel 4: attn_scores[b][u][k] = Q[b, topi[b][u]] . K[b][k] * 0.125
// ---------------------------------------------------------------------------
__global__ __launch_bounds__(256) void scores_kernel(const float* __restrict__ Q,
                                                     const float* __restrict__ K,
                                                     const int* __restrict__ topi,
                                                     float* __restrict__ scores) {
  int b = blockIdx.y;
  int k = blockIdx.x * 256 + threadIdx.x;
  __shared__ float Qr[UU][DD];  // 10 KB
  for (int li = threadIdx.x; li < UU * DD; li += 256) {
    int u = li >> 6, d = li & 63;
    Qr[u][d] = Q[((size_t)b * LL + topi[b * UU + u]) * DD + d];
  }
  __syncthreads();
  float4 kr[16];
  const float4* Krow = (const float4*)(K + ((size_t)b * LL + k) * DD);
#pragma unroll
  for (int i = 0; i < 16; ++i) kr[i] = Krow[i];
  for (int u = 0; u < UU; ++u) {
    float s = 0.f;
#pragma unroll
    for (int i = 0; i < 16; ++i) {
      float4 qv = *(const float4*)&Qr[u][i << 2];  // broadcast read
      s += qv.x * kr[i].x + qv.y * kr[i].y + qv.z * kr[i].z + qv.w * kr[i].w;
    }
    scores[((size_t)(b * UU + u)) * LL + k] = s * 0.125f;
  }
}

// ---------------------------------------------------------------------------
// Kernel 5: softmax over scores row + P.V  -> attn_output[b][u][:]
// ---------------------------------------------------------------------------
__global__ __launch_bounds__(256) void softmax_pv_kernel(const float* __restrict__ scores,
                                                         const float* __restrict__ V,
                                                         float* __restrict__ out) {
  int u = blockIdx.x, b = blockIdx.y;
  int tid = threadIdx.x;
  const float* srow = scores + ((size_t)(b * UU + u)) * LL;
  __shared__ float p[LL];     // 8 KB
  __shared__ float red[256];

  float m = NEG_BIG;
  for (int j = tid; j < LL; j += 256) m = fmaxf(m, srow[j]);
  red[tid] = m;
  __syncthreads();
  for (int s = 128; s > 0; s >>= 1) {
    if (tid < s) red[tid] = fmaxf(red[tid], red[tid + s]);
    __syncthreads();
  }
  float smax = red[0];
  __syncthreads();

  float lsum = 0.f;
  for (int j = tid; j < LL; j += 256) {
    float e = __expf(srow[j] - smax);
    p[j] = e;
    lsum += e;
  }
  red[tid] = lsum;
  __syncthreads();
  for (int s = 128; s > 0; s >>= 1) {
    if (tid < s) red[tid] += red[tid + s];
    __syncthreads();
  }
  float inv = 1.0f / red[0];
  __syncthreads();

  int d = tid & 63, c = tid >> 6;
  float acc = 0.f;
  const float* Vb = V + (size_t)b * LL * DD;
  int k0 = c * (LL / 4), k1 = k0 + (LL / 4);
  for (int k = k0; k < k1; ++k) acc += p[k] * Vb[(size_t)k * DD + d];
  red[tid] = acc;
  __syncthreads();
  if (c == 0)
    out[((size_t)(b * UU) + u) * DD + d] =
        (red[d] + red[64 + d] + red[128 + d] + red[192 + d]) * inv;
}

// ---------------------------------------------------------------------------
extern "C" void kernel_launch(void* const* d_in, const int* in_sizes, int n_in,
                              void* d_out, int out_size, void* d_ws, size_t ws_size,
                              hipStream_t stream) {
  (void)in_sizes; (void)n_in; (void)out_size;
  const float* Q = (const float*)d_in[0];
  const float* K = (const float*)d_in[1];
  const float* V = (const float*)d_in[2];
  const int* idx = (const int*)d_in[3];

  float* out = (float*)d_out;                 // attn_output region: B*U*D floats
  float* scores = out + (size_t)BB * UU * DD; // attn_scores region: B*U*L floats

  // Scratch: prefer ws; fall back to aliasing dead regions of d_out.
  // Alias ordering is safe: M/Ksum live in the scores region (dead until
  // scores_kernel), topi lives in the attn_output region (dead until
  // softmax_pv_kernel, which no longer needs topi).
  size_t need = (size_t)(BB * LL + BB * DD) * sizeof(float) + (size_t)(BB * UU) * sizeof(int);
  float* M; float* Ksum; int* topi;
  if (ws_size >= need) {
    M = (float*)d_ws;
    Ksum = M + BB * LL;
    topi = (int*)(Ksum + BB * DD);
  } else {
    M = scores;
    Ksum = scores + BB * LL;
    topi = (int*)out;
  }

  ksum_kernel<<<BB, 256, 0, stream>>>(K, idx, Ksum);
  m_kernel<<<dim3(LL / 64, BB), 256, 0, stream>>>(Q, K, idx, Ksum, M);
  topk_kernel<<<BB, 256, 0, stream>>>(M, topi);
  scores_kernel<<<dim3(LL / 256, BB), 256, 0, stream>>>(Q, K, topi, scores);
  softmax_pv_kernel<<<dim3(UU, BB), 256, 0, stream>>>(scores, V, out);
}

// Round 2
// 582.699 us; speedup vs baseline: 1.4129x; 1.4129x over previous
//
#include <hip/hip_runtime.h>
#include <math.h>

#define BB 32
#define LL 2048
#define DD 64
#define UU 40
#define NEG_BIG (-3.0e38f)

// ---------------------------------------------------------------------------
// Kernel 1: partial Ksum. Kpart[b][p][d] = sum_{j in p-th 128-slice} K[b,idx[j],d]
// 512 blocks -> latency hidden (was 32 blocks, pure-latency bound).
// ---------------------------------------------------------------------------
__global__ __launch_bounds__(256) void ksum_kernel(const float* __restrict__ K,
                                                   const int* __restrict__ idx,
                                                   float* __restrict__ Kpart) {
  int p = blockIdx.x;  // 0..15
  int b = blockIdx.y;
  int tid = threadIdx.x;
  int d = tid & 63;
  int c = tid >> 6;  // 0..3
  const float* Kb = K + (size_t)b * LL * DD;
  float acc = 0.f;
  int j0 = p * 128 + c * 32;
#pragma unroll 4
  for (int t = 0; t < 32; ++t) {
    acc += Kb[(size_t)idx[j0 + t] * DD + d];  // 64 lanes coalesced per row
  }
  __shared__ float red[256];
  red[tid] = acc;
  __syncthreads();
  if (c == 0) Kpart[(b * 16 + p) * 64 + d] = red[d] + red[64 + d] + red[128 + d] + red[192 + d];
}

// ---------------------------------------------------------------------------
// Kernel 2: M[b][q] = max_j (Q[b,q]·K[b,idx[j]]) - (Q[b,q]·Ksum[b]) / L
// 128x128 tile, 8q x 8k per thread. Row-major LDS tiles padded to 68 floats:
//   - staging: coalesced global float4 -> identity-layout LDS write, banks
//     uniform (8 dwords/bank per b128 op)
//   - compute reads along d: addr = 68*q + d -> bank (4q+d)%32, q = tx+16i
//     spans 16 strided values -> uniform 2 dwords/bank. Conflict-free.
// ---------------------------------------------------------------------------
__global__ __launch_bounds__(256) void m_kernel(const float* __restrict__ Q,
                                                const float* __restrict__ K,
                                                const int* __restrict__ idx,
                                                const float* __restrict__ Kpart,
                                                float* __restrict__ M) {
  __shared__ float Qs[128][68];   // 34816 B
  __shared__ float Ks[128][68];   // 34816 B
  __shared__ float KsumS[64];
  __shared__ float red[128][17];  // 8704 B

  int b = blockIdx.y;
  int q0 = blockIdx.x * 128;
  int tid = threadIdx.x;
  int tx = tid & 15;   // query group: q = tx + 16*i
  int ty = tid >> 4;   // key group:   k = ty + 16*j

  // combine Ksum partials (stream-ordered after ksum_kernel)
  if (tid < 64) {
    float s = 0.f;
#pragma unroll
    for (int p = 0; p < 16; ++p) s += Kpart[(b * 16 + p) * 64 + tid];
    KsumS[tid] = s;
  }

  // stage Q tile (row-major, once)
#pragma unroll
  for (int it = 0; it < 8; ++it) {
    int li = it * 256 + tid;        // 0..2047
    int q = li >> 4;                // 0..127
    int dd = (li & 15) << 2;        // 0..60
    float4 v = *(const float4*)(Q + ((size_t)b * LL + q0 + q) * DD + dd);
    *(float4*)&Qs[q][dd] = v;
  }

  float mx[8];
#pragma unroll
  for (int i = 0; i < 8; ++i) mx[i] = NEG_BIG;

  for (int c = 0; c < LL / 128; ++c) {
    __syncthreads();  // protect Ks from previous chunk's readers (also covers Q staging on c==0)
#pragma unroll
    for (int it = 0; it < 8; ++it) {
      int li = it * 256 + tid;
      int kk = li >> 4;
      int dd = (li & 15) << 2;
      int gk = idx[c * 128 + kk];
      float4 v = *(const float4*)(K + ((size_t)b * LL + gk) * DD + dd);
      *(float4*)&Ks[kk][dd] = v;
    }
    __syncthreads();

    float acc[8][8];
#pragma unroll
    for (int i = 0; i < 8; ++i)
#pragma unroll
      for (int j = 0; j < 8; ++j) acc[i][j] = 0.f;

#pragma unroll 2
    for (int dd = 0; dd < 64; dd += 4) {
      float4 qf[8];
#pragma unroll
      for (int i = 0; i < 8; ++i) qf[i] = *(const float4*)&Qs[tx + 16 * i][dd];
#pragma unroll
      for (int j = 0; j < 8; ++j) {
        float4 kf = *(const float4*)&Ks[ty + 16 * j][dd];
#pragma unroll
        for (int i = 0; i < 8; ++i) {
          acc[i][j] += qf[i].x * kf.x + qf[i].y * kf.y + qf[i].z * kf.z + qf[i].w * kf.w;
        }
      }
    }
#pragma unroll
    for (int i = 0; i < 8; ++i) {
      float m01 = fmaxf(fmaxf(acc[i][0], acc[i][1]), fmaxf(acc[i][2], acc[i][3]));
      float m23 = fmaxf(fmaxf(acc[i][4], acc[i][5]), fmaxf(acc[i][6], acc[i][7]));
      mx[i] = fmaxf(mx[i], fmaxf(m01, m23));
    }
  }

  __syncthreads();
#pragma unroll
  for (int i = 0; i < 8; ++i) red[tx + 16 * i][ty] = mx[i];
  __syncthreads();

  if (tid < 128) {
    int q = tid;
    float m = red[q][0];
#pragma unroll
    for (int t = 1; t < 16; ++t) m = fmaxf(m, red[q][t]);
    float s = 0.f;
#pragma unroll 16
    for (int d = 0; d < 64; ++d) s += Qs[q][d] * KsumS[d];
    M[b * LL + q0 + q] = m - s * (1.0f / (float)LL);
  }
}

// ---------------------------------------------------------------------------
// Kernel 3: per-batch top-40 of M, exact lax.top_k order (desc, ties->low idx)
// Shuffle-based reduction: 2 syncs per extraction instead of 16.
// ---------------------------------------------------------------------------
__global__ __launch_bounds__(256) void topk_kernel(const float* __restrict__ M,
                                                   int* __restrict__ topi) {
  int b = blockIdx.x;
  int tid = threadIdx.x;
  __shared__ float mv[LL];
  __shared__ float wv[4];
  __shared__ int wi[4];
  for (int j = tid; j < LL; j += 256) mv[j] = M[b * LL + j];
  __syncthreads();
  for (int t = 0; t < UU; ++t) {
    float bv = NEG_BIG;
    int bi = 0x7fffffff;
    for (int j = tid; j < LL; j += 256) {
      float v = mv[j];
      if (v > bv) { bv = v; bi = j; }  // ascending scan keeps lowest index on ties
    }
#pragma unroll
    for (int off = 32; off > 0; off >>= 1) {
      float ov = __shfl_down(bv, off);
      int oi = __shfl_down(bi, off);
      if (ov > bv || (ov == bv && oi < bi)) { bv = ov; bi = oi; }
    }
    if ((tid & 63) == 0) { wv[tid >> 6] = bv; wi[tid >> 6] = bi; }
    __syncthreads();
    if (tid == 0) {
#pragma unroll
      for (int w = 1; w < 4; ++w) {
        if (wv[w] > bv || (wv[w] == bv && wi[w] < bi)) { bv = wv[w]; bi = wi[w]; }
      }
      topi[b * UU + t] = bi;
      mv[bi] = NEG_BIG;
    }
    __syncthreads();
  }
}

// ---------------------------------------------------------------------------
// Kernel 4: attn_scores[b][u][k] = Q[b, topi[b][u]] . K[b][k] * 0.125
// ---------------------------------------------------------------------------
__global__ __launch_bounds__(256) void scores_kernel(const float* __restrict__ Q,
                                                     const float* __restrict__ K,
                                                     const int* __restrict__ topi,
                                                     float* __restrict__ scores) {
  int b = blockIdx.y;
  int k = blockIdx.x * 256 + threadIdx.x;
  __shared__ float Qr[UU][DD];  // 10 KB
  for (int li = threadIdx.x; li < UU * DD; li += 256) {
    int u = li >> 6, d = li & 63;
    Qr[u][d] = Q[((size_t)b * LL + topi[b * UU + u]) * DD + d];
  }
  __syncthreads();
  float4 kr[16];
  const float4* Krow = (const float4*)(K + ((size_t)b * LL + k) * DD);
#pragma unroll
  for (int i = 0; i < 16; ++i) kr[i] = Krow[i];
  for (int u = 0; u < UU; ++u) {
    float s = 0.f;
#pragma unroll
    for (int i = 0; i < 16; ++i) {
      float4 qv = *(const float4*)&Qr[u][i << 2];  // broadcast read: free
      s += qv.x * kr[i].x + qv.y * kr[i].y + qv.z * kr[i].z + qv.w * kr[i].w;
    }
    scores[((size_t)(b * UU + u)) * LL + k] = s * 0.125f;
  }
}

// ---------------------------------------------------------------------------
// Kernel 5: softmax + P.V for 4 u-rows per block (amortize V reads 4x).
// ---------------------------------------------------------------------------
__global__ __launch_bounds__(256) void softmax_pv_kernel(const float* __restrict__ scores,
                                                         const float* __restrict__ V,
                                                         float* __restrict__ out) {
  int b = blockIdx.y;
  int u0 = blockIdx.x * 4;
  int tid = threadIdx.x;
  __shared__ float p[4][LL];  // 32 KB
  __shared__ float wred[4];
  __shared__ float inv_s[4];
  __shared__ float r2[256];

#pragma unroll
  for (int uu = 0; uu < 4; ++uu) {
    const float* srow = scores + ((size_t)(b * UU + u0 + uu)) * LL;
    // block max via shuffle + LDS
    float m = NEG_BIG;
    for (int j = tid; j < LL; j += 256) m = fmaxf(m, srow[j]);
#pragma unroll
    for (int off = 32; off > 0; off >>= 1) m = fmaxf(m, __shfl_down(m, off));
    if ((tid & 63) == 0) wred[tid >> 6] = m;
    __syncthreads();
    float smax = fmaxf(fmaxf(wred[0], wred[1]), fmaxf(wred[2], wred[3]));
    __syncthreads();  // before wred reuse
    // exp + block sum
    float ls = 0.f;
    for (int j = tid; j < LL; j += 256) {
      float e = __expf(srow[j] - smax);
      p[uu][j] = e;
      ls += e;
    }
#pragma unroll
    for (int off = 32; off > 0; off >>= 1) ls += __shfl_down(ls, off);
    if ((tid & 63) == 0) wred[tid >> 6] = ls;
    __syncthreads();
    if (tid == 0) inv_s[uu] = 1.0f / (wred[0] + wred[1] + wred[2] + wred[3]);
    __syncthreads();
  }

  // P.V: thread (d, c) accumulates 4 u-rows over its k-range
  int d = tid & 63, c = tid >> 6;
  float acc[4] = {0.f, 0.f, 0.f, 0.f};
  const float* Vb = V + (size_t)b * LL * DD;
  int k0 = c * (LL / 4), k1 = k0 + (LL / 4);
  for (int k = k0; k < k1; ++k) {
    float v = Vb[(size_t)k * DD + d];  // coalesced; p reads are wave-broadcast
#pragma unroll
    for (int uu = 0; uu < 4; ++uu) acc[uu] += p[uu][k] * v;
  }
#pragma unroll
  for (int uu = 0; uu < 4; ++uu) {
    r2[tid] = acc[uu];
    __syncthreads();
    if (c == 0) {
      out[((size_t)(b * UU) + u0 + uu) * DD + d] =
          (r2[d] + r2[64 + d] + r2[128 + d] + r2[192 + d]) * inv_s[uu];
    }
    __syncthreads();
  }
}

// ---------------------------------------------------------------------------
extern "C" void kernel_launch(void* const* d_in, const int* in_sizes, int n_in,
                              void* d_out, int out_size, void* d_ws, size_t ws_size,
                              hipStream_t stream) {
  (void)in_sizes; (void)n_in; (void)out_size;
  const float* Q = (const float*)d_in[0];
  const float* K = (const float*)d_in[1];
  const float* V = (const float*)d_in[2];
  const int* idx = (const int*)d_in[3];

  float* out = (float*)d_out;                 // attn_output region: B*U*D floats
  float* scores = out + (size_t)BB * UU * DD; // attn_scores region: B*U*L floats

  // Scratch: prefer ws; fall back to aliasing dead regions of d_out.
  // M/Kpart live in the scores region (dead until scores_kernel);
  // topi lives in the attn_output region (dead until softmax_pv overwrites it,
  // by which time topi is no longer needed).
  size_t need = (size_t)(BB * LL + BB * 16 * DD) * sizeof(float) + (size_t)(BB * UU) * sizeof(int);
  float* M; float* Kpart; int* topi;
  if (ws_size >= need) {
    M = (float*)d_ws;
    Kpart = M + BB * LL;
    topi = (int*)(Kpart + BB * 16 * DD);
  } else {
    M = scores;
    Kpart = scores + BB * LL;
    topi = (int*)out;
  }

  ksum_kernel<<<dim3(16, BB), 256, 0, stream>>>(K, idx, Kpart);
  m_kernel<<<dim3(LL / 128, BB), 256, 0, stream>>>(Q, K, idx, Kpart, M);
  topk_kernel<<<BB, 256, 0, stream>>>(M, topi);
  scores_kernel<<<dim3(LL / 256, BB), 256, 0, stream>>>(Q, K, topi, scores);
  softmax_pv_kernel<<<dim3(UU / 4, BB), 256, 0, stream>>>(scores, V, out);
}

// Round 3
// 411.738 us; speedup vs baseline: 1.9995x; 1.4152x over previous
//
#include <hip/hip_runtime.h>
#include <math.h>

#define BB 32
#define LL 2048
#define DD 64
#define UU 40
#define CC 64            // bf16-phase candidates per batch
#define NEG_BIG (-3.0e38f)

typedef __attribute__((ext_vector_type(8))) short short8;
typedef __attribute__((ext_vector_type(4))) float f32x4;
typedef unsigned long long ull;
typedef unsigned int uint;
typedef unsigned short ushort_t;

__device__ __forceinline__ unsigned short f2bf(float f) {
  uint u = __float_as_uint(f);
  u += 0x7FFFu + ((u >> 16) & 1u);   // RNE
  return (unsigned short)(u >> 16);
}
__device__ __forceinline__ uint fsort(float f) {
  uint u = __float_as_uint(f);
  return (u & 0x80000000u) ? ~u : (u | 0x80000000u);  // monotonic map
}
__device__ __forceinline__ ull shfl_xor_u64(ull x, int m) {
  uint lo = (uint)x, hi = (uint)(x >> 32);
  lo = __shfl_xor(lo, m);
  hi = __shfl_xor(hi, m);
  return ((ull)hi << 32) | lo;
}

// ---------------------------------------------------------------------------
// Kernel 1: partial Ksum over gathered rows. Kpart[b][p][d].
// ---------------------------------------------------------------------------
__global__ __launch_bounds__(256) void ksum_kernel(const float* __restrict__ K,
                                                   const int* __restrict__ idx,
                                                   float* __restrict__ Kpart) {
  int p = blockIdx.x, b = blockIdx.y, tid = threadIdx.x;
  int d = tid & 63, c = tid >> 6;
  const float* Kb = K + (size_t)b * LL * DD;
  float acc = 0.f;
  int j0 = p * 128 + c * 32;
#pragma unroll 4
  for (int t = 0; t < 32; ++t) acc += Kb[(size_t)idx[j0 + t] * DD + d];
  __shared__ float red[256];
  red[tid] = acc;
  __syncthreads();
  if (c == 0) Kpart[(b * 16 + p) * 64 + d] = red[d] + red[64 + d] + red[128 + d] + red[192 + d];
}

// ---------------------------------------------------------------------------
// Kernel 2: convert Q -> bf16 (Qb) and gathered K -> bf16 (Kg = K[idx[j]]).
// ---------------------------------------------------------------------------
__global__ __launch_bounds__(256) void prep_kernel(const float* __restrict__ Q,
                                                   const float* __restrict__ K,
                                                   const int* __restrict__ idx,
                                                   ushort_t* __restrict__ Qb,
                                                   ushort_t* __restrict__ Kg) {
  int p = blockIdx.x, b = blockIdx.y, t = threadIdx.x;
  int g = t & 7;  // 16B group = 8 elements
#pragma unroll
  for (int it = 0; it < 4; ++it) {
    int r = p * 128 + it * 32 + (t >> 3);
    {  // Q row r
      const float* src = Q + ((size_t)b * LL + r) * DD + g * 8;
      float4 a = *(const float4*)src;
      float4 c4 = *(const float4*)(src + 4);
      int4 o;
      o.x = (int)(f2bf(a.x) | ((uint)f2bf(a.y) << 16));
      o.y = (int)(f2bf(a.z) | ((uint)f2bf(a.w) << 16));
      o.z = (int)(f2bf(c4.x) | ((uint)f2bf(c4.y) << 16));
      o.w = (int)(f2bf(c4.z) | ((uint)f2bf(c4.w) << 16));
      *(int4*)(Qb + ((size_t)b * LL + r) * DD + g * 8) = o;
    }
    {  // gathered K row r
      int gk = idx[r];
      const float* src = K + ((size_t)b * LL + gk) * DD + g * 8;
      float4 a = *(const float4*)src;
      float4 c4 = *(const float4*)(src + 4);
      int4 o;
      o.x = (int)(f2bf(a.x) | ((uint)f2bf(a.y) << 16));
      o.y = (int)(f2bf(a.z) | ((uint)f2bf(a.w) << 16));
      o.z = (int)(f2bf(c4.x) | ((uint)f2bf(c4.y) << 16));
      o.w = (int)(f2bf(c4.z) | ((uint)f2bf(c4.w) << 16));
      *(int4*)(Kg + ((size_t)b * LL + r) * DD + g * 8) = o;
    }
  }
}

// ---------------------------------------------------------------------------
// Kernel 3: bf16 MFMA M-scores. Mb[b][q] = max_j(Q.K_sample[j]) - (Q.Ksum)/L.
// 16x16x32 bf16 MFMA (verified layouts). Block: 128 q-rows, 4 waves, each
// wave owns a 64q x 64k quadrant of each 128-key chunk.
// LDS rows are 128B with 16B groups XOR-swizzled by (row&7): conflict-free
// b128 fragment reads AND conflict-free staging writes.
// ---------------------------------------------------------------------------
__global__ __launch_bounds__(256) void mfma_m_kernel(const ushort_t* __restrict__ Qb,
                                                     const ushort_t* __restrict__ Kg,
                                                     const float* __restrict__ Q,
                                                     const float* __restrict__ Kpart,
                                                     float* __restrict__ Mb) {
  __shared__ __align__(16) ushort_t Qs[128 * 64];  // 16 KB, swizzled
  __shared__ __align__(16) ushort_t Ks[128 * 64];  // 16 KB, swizzled
  __shared__ float Mmax[2][128];
  __shared__ float KsumS[64];

  int b = blockIdx.y, q0 = blockIdx.x * 128;
  int t = threadIdx.x;
  int w = t >> 6, L = t & 63;

  if (t < 64) {
    float s = 0.f;
#pragma unroll
    for (int p = 0; p < 16; ++p) s += Kpart[(b * 16 + p) * 64 + t];
    KsumS[t] = s;
  }

  // stage Q tile once (swizzled)
  {
    int g = t & 7;
#pragma unroll
    for (int it = 0; it < 4; ++it) {
      int r = it * 32 + (t >> 3);
      int4 v = *(const int4*)(Qb + ((size_t)b * LL + q0 + r) * DD + g * 8);
      *(int4*)&Qs[r * 64 + 8 * (g ^ (r & 7))] = v;
    }
  }

  f32x4 mx[4];
#pragma unroll
  for (int i = 0; i < 4; ++i) mx[i] = (f32x4){NEG_BIG, NEG_BIG, NEG_BIG, NEG_BIG};

  const int waveQ = 64 * (w & 1);
  const int waveK = 64 * (w >> 1);
  const int lm = L & 15;   // m / n within 16-tile
  const int lq = L >> 4;   // k quad

  for (int c = 0; c < LL / 128; ++c) {
    __syncthreads();  // prior readers done
    {
      int g = t & 7;
#pragma unroll
      for (int it = 0; it < 4; ++it) {
        int r = it * 32 + (t >> 3);
        int4 v = *(const int4*)(Kg + ((size_t)b * LL + c * 128 + r) * DD + g * 8);
        *(int4*)&Ks[r * 64 + 8 * (g ^ (r & 7))] = v;
      }
    }
    __syncthreads();

    f32x4 acc[4][4];
#pragma unroll
    for (int i = 0; i < 4; ++i)
#pragma unroll
      for (int j = 0; j < 4; ++j) acc[i][j] = (f32x4){0.f, 0.f, 0.f, 0.f};

#pragma unroll
    for (int s = 0; s < 2; ++s) {
      int g = 4 * s + lq;  // 16B group of the needed 8 bf16
      short8 A[4];
#pragma unroll
      for (int qt = 0; qt < 4; ++qt) {
        int r = waveQ + 16 * qt + lm;
        A[qt] = *(const short8*)&Qs[r * 64 + 8 * (g ^ (r & 7))];
      }
#pragma unroll
      for (int kt = 0; kt < 4; ++kt) {
        int rB = waveK + 16 * kt + lm;
        short8 Bf = *(const short8*)&Ks[rB * 64 + 8 * (g ^ (rB & 7))];
#pragma unroll
        for (int qt = 0; qt < 4; ++qt) {
          acc[qt][kt] = __builtin_amdgcn_mfma_f32_16x16x32_bf16(A[qt], Bf, acc[qt][kt], 0, 0, 0);
        }
      }
    }
#pragma unroll
    for (int qt = 0; qt < 4; ++qt)
#pragma unroll
      for (int kt = 0; kt < 4; ++kt) {
#pragma unroll
        for (int r4 = 0; r4 < 4; ++r4) mx[qt][r4] = fmaxf(mx[qt][r4], acc[qt][kt][r4]);
      }
  }

  // reduce across the 16 columns (lanes differing in bits 0..3 share rows)
#pragma unroll
  for (int qt = 0; qt < 4; ++qt) {
#pragma unroll
    for (int r4 = 0; r4 < 4; ++r4) {
      float v = mx[qt][r4];
      v = fmaxf(v, __shfl_xor(v, 1));
      v = fmaxf(v, __shfl_xor(v, 2));
      v = fmaxf(v, __shfl_xor(v, 4));
      v = fmaxf(v, __shfl_xor(v, 8));
      mx[qt][r4] = v;
    }
  }
  if (lm < 4) {
    int qt = lm;
#pragma unroll
    for (int r4 = 0; r4 < 4; ++r4) {
      Mmax[w >> 1][waveQ + 16 * qt + 4 * lq + r4] = mx[qt][r4];
    }
  }
  __syncthreads();

  if (t < 128) {
    float m = fmaxf(Mmax[0][t], Mmax[1][t]);
    const float4* Qr = (const float4*)(Q + ((size_t)b * LL + q0 + t) * DD);
    float s = 0.f;
#pragma unroll
    for (int i = 0; i < 16; ++i) {
      float4 qv = Qr[i];
      s += qv.x * KsumS[4 * i] + qv.y * KsumS[4 * i + 1] + qv.z * KsumS[4 * i + 2] +
           qv.w * KsumS[4 * i + 3];
    }
    Mb[b * LL + q0 + t] = m - s * (1.0f / (float)LL);
  }
}

// ---------------------------------------------------------------------------
// Kernel 4: per-batch top-64 candidate set by Mb (any tie order; set only).
// Values held in registers (8/thread); 64 extraction rounds.
// ---------------------------------------------------------------------------
__global__ __launch_bounds__(256) void cand_kernel(const float* __restrict__ Mb,
                                                   int* __restrict__ cand) {
  int b = blockIdx.x, t = threadIdx.x;
  int w = t >> 6;
  float v[8];
#pragma unroll
  for (int i = 0; i < 8; ++i) v[i] = Mb[b * LL + t + 256 * i];
  __shared__ ull warr[4];
  __shared__ ull winls;
  for (int round = 0; round < CC; ++round) {
    float bv = v[0];
    int bi = 0;
#pragma unroll
    for (int i = 1; i < 8; ++i)
      if (v[i] > bv) { bv = v[i]; bi = i; }
    ull key = ((ull)fsort(bv) << 32) | (ull)(uint)(t + 256 * bi);
#pragma unroll
    for (int m = 1; m < 64; m <<= 1) {
      ull o = shfl_xor_u64(key, m);
      if (o > key) key = o;
    }
    if ((t & 63) == 0) warr[w] = key;
    __syncthreads();
    if (t == 0) {
      ull k = warr[0];
#pragma unroll
      for (int i = 1; i < 4; ++i)
        if (warr[i] > k) k = warr[i];
      winls = k;
      cand[b * CC + round] = (int)(k & 0xFFFFFFFFull);
    }
    __syncthreads();
    int wj = (int)(winls & 0xFFFFFFFFull);
    if (t == (wj & 255)) v[wj >> 8] = NEG_BIG;
  }
}

// ---------------------------------------------------------------------------
// Kernel 5: fp32 rescue partial maxes. Block (seg, b): 256 gathered keys;
// Mpart[b][u][seg] = max over segment of Q[cand[u]] . K[idx[j]].
// ---------------------------------------------------------------------------
__global__ __launch_bounds__(256) void rescue_kernel(const float* __restrict__ Q,
                                                     const float* __restrict__ K,
                                                     const int* __restrict__ idx,
                                                     const int* __restrict__ cand,
                                                     float* __restrict__ Mpart) {
  int seg = blockIdx.x, b = blockIdx.y, t = threadIdx.x;
  int w = t >> 6;
  __shared__ int cidx[CC];
  __shared__ float Qc[CC][DD];   // 16 KB; reads are wave-broadcast
  __shared__ float redm[CC][4];
  if (t < CC) cidx[t] = cand[b * CC + t];
  __syncthreads();
  for (int li = t; li < CC * 16; li += 256) {
    int row = li >> 4, g4 = li & 15;
    *(float4*)&Qc[row][4 * g4] =
        *(const float4*)(Q + ((size_t)b * LL + cidx[row]) * DD + 4 * g4);
  }
  __syncthreads();

  int key = idx[seg * 256 + t];
  float4 kr[16];
  const float4* Krow = (const float4*)(K + ((size_t)b * LL + key) * DD);
#pragma unroll
  for (int i = 0; i < 16; ++i) kr[i] = Krow[i];

#pragma unroll 2
  for (int u = 0; u < CC; ++u) {
    const float4* qp = (const float4*)&Qc[u][0];
    float d = 0.f;
#pragma unroll
    for (int i = 0; i < 16; ++i) {
      float4 qv = qp[i];
      d = fmaf(qv.x, kr[i].x, d);
      d = fmaf(qv.y, kr[i].y, d);
      d = fmaf(qv.z, kr[i].z, d);
      d = fmaf(qv.w, kr[i].w, d);
    }
#pragma unroll
    for (int m = 1; m < 64; m <<= 1) d = fmaxf(d, __shfl_xor(d, m));
    if ((t & 63) == 0) redm[u][w] = d;
  }
  __syncthreads();
  if (t < CC) {
    float m = fmaxf(fmaxf(redm[t][0], redm[t][1]), fmaxf(redm[t][2], redm[t][3]));
    Mpart[((size_t)b * CC + t) * 8 + seg] = m;
  }
}

// ---------------------------------------------------------------------------
// Kernel 6: combine partials + exact fp32 mean term; exact top-40 with
// lax.top_k tie semantics (desc value, ties -> lowest index). One wave/batch.
// ---------------------------------------------------------------------------
__global__ __launch_bounds__(64) void select_kernel(const float* __restrict__ Q,
                                                    const float* __restrict__ Kpart,
                                                    const int* __restrict__ cand,
                                                    const float* __restrict__ Mpart,
                                                    int* __restrict__ topi) {
  int b = blockIdx.x, t = threadIdx.x;  // 64 threads = 1 wave
  __shared__ float KsumS[64];
  {
    float s = 0.f;
#pragma unroll
    for (int p = 0; p < 16; ++p) s += Kpart[(b * 16 + p) * 64 + t];
    KsumS[t] = s;
  }
  __syncthreads();
  int ci = cand[b * CC + t];
  float m = NEG_BIG;
#pragma unroll
  for (int s = 0; s < 8; ++s) m = fmaxf(m, Mpart[((size_t)b * CC + t) * 8 + s]);
  const float4* Qr = (const float4*)(Q + ((size_t)b * LL + ci) * DD);
  float s = 0.f;
#pragma unroll
  for (int i = 0; i < 16; ++i) {
    float4 qv = Qr[i];
    s += qv.x * KsumS[4 * i] + qv.y * KsumS[4 * i + 1] + qv.z * KsumS[4 * i + 2] +
         qv.w * KsumS[4 * i + 3];
  }
  float Mf = m - s * (1.0f / (float)LL);
  ull key = ((ull)fsort(Mf) << 32) | (ull)(uint)(2047 - ci);  // ties -> lowest idx
  for (int round = 0; round < UU; ++round) {
    ull k = key;
#pragma unroll
    for (int mk = 1; mk < 64; mk <<= 1) {
      ull o = shfl_xor_u64(k, mk);
      if (o > k) k = o;
    }
    int wci = 2047 - (int)(k & 0xFFFFFFFFull);
    if (t == 0) topi[b * UU + round] = wci;
    if (ci == wci) key = 0;  // remove mine
  }
}

// ---------------------------------------------------------------------------
// Kernel 7: attn_scores[b][u][k] = Q[b, topi[b][u]] . K[b][k] * 0.125
// ---------------------------------------------------------------------------
__global__ __launch_bounds__(256) void scores_kernel(const float* __restrict__ Q,
                                                     const float* __restrict__ K,
                                                     const int* __restrict__ topi,
                                                     float* __restrict__ scores) {
  int b = blockIdx.y;
  int k = blockIdx.x * 256 + threadIdx.x;
  __shared__ float Qr[UU][DD];
  for (int li = threadIdx.x; li < UU * DD; li += 256) {
    int u = li >> 6, d = li & 63;
    Qr[u][d] = Q[((size_t)b * LL + topi[b * UU + u]) * DD + d];
  }
  __syncthreads();
  float4 kr[16];
  const float4* Krow = (const float4*)(K + ((size_t)b * LL + k) * DD);
#pragma unroll
  for (int i = 0; i < 16; ++i) kr[i] = Krow[i];
  for (int u = 0; u < UU; ++u) {
    float s = 0.f;
#pragma unroll
    for (int i = 0; i < 16; ++i) {
      float4 qv = *(const float4*)&Qr[u][i << 2];
      s += qv.x * kr[i].x + qv.y * kr[i].y + qv.z * kr[i].z + qv.w * kr[i].w;
    }
    scores[((size_t)(b * UU + u)) * LL + k] = s * 0.125f;
  }
}

// ---------------------------------------------------------------------------
// Kernel 8: softmax + P.V for 4 u-rows per block.
// ---------------------------------------------------------------------------
__global__ __launch_bounds__(256) void softmax_pv_kernel(const float* __restrict__ scores,
                                                         const float* __restrict__ V,
                                                         float* __restrict__ out) {
  int b = blockIdx.y;
  int u0 = blockIdx.x * 4;
  int tid = threadIdx.x;
  __shared__ float p[4][LL];
  __shared__ float wred[4];
  __shared__ float inv_s[4];
  __shared__ float r2[256];

#pragma unroll
  for (int uu = 0; uu < 4; ++uu) {
    const float* srow = scores + ((size_t)(b * UU + u0 + uu)) * LL;
    float m = NEG_BIG;
    for (int j = tid; j < LL; j += 256) m = fmaxf(m, srow[j]);
#pragma unroll
    for (int off = 32; off > 0; off >>= 1) m = fmaxf(m, __shfl_down(m, off));
    if ((tid & 63) == 0) wred[tid >> 6] = m;
    __syncthreads();
    float smax = fmaxf(fmaxf(wred[0], wred[1]), fmaxf(wred[2], wred[3]));
    __syncthreads();
    float ls = 0.f;
    for (int j = tid; j < LL; j += 256) {
      float e = __expf(srow[j] - smax);
      p[uu][j] = e;
      ls += e;
    }
#pragma unroll
    for (int off = 32; off > 0; off >>= 1) ls += __shfl_down(ls, off);
    if ((tid & 63) == 0) wred[tid >> 6] = ls;
    __syncthreads();
    if (tid == 0) inv_s[uu] = 1.0f / (wred[0] + wred[1] + wred[2] + wred[3]);
    __syncthreads();
  }

  int d = tid & 63, c = tid >> 6;
  float acc[4] = {0.f, 0.f, 0.f, 0.f};
  const float* Vb = V + (size_t)b * LL * DD;
  int k0 = c * (LL / 4), k1 = k0 + (LL / 4);
  for (int k = k0; k < k1; ++k) {
    float v = Vb[(size_t)k * DD + d];
#pragma unroll
    for (int uu = 0; uu < 4; ++uu) acc[uu] += p[uu][k] * v;
  }
#pragma unroll
  for (int uu = 0; uu < 4; ++uu) {
    r2[tid] = acc[uu];
    __syncthreads();
    if (c == 0) {
      out[((size_t)(b * UU) + u0 + uu) * DD + d] =
          (r2[d] + r2[64 + d] + r2[128 + d] + r2[192 + d]) * inv_s[uu];
    }
    __syncthreads();
  }
}

// ========================= fp32 fallback (round-2 path) ====================
__global__ __launch_bounds__(256) void m_kernel(const float* __restrict__ Q,
                                                const float* __restrict__ K,
                                                const int* __restrict__ idx,
                                                const float* __restrict__ Kpart,
                                                float* __restrict__ M) {
  __shared__ float Qs[128][68];
  __shared__ float Ks[128][68];
  __shared__ float KsumS[64];
  __shared__ float red[128][17];
  int b = blockIdx.y, q0 = blockIdx.x * 128, tid = threadIdx.x;
  int tx = tid & 15, ty = tid >> 4;
  if (tid < 64) {
    float s = 0.f;
#pragma unroll
    for (int p = 0; p < 16; ++p) s += Kpart[(b * 16 + p) * 64 + tid];
    KsumS[tid] = s;
  }
#pragma unroll
  for (int it = 0; it < 8; ++it) {
    int li = it * 256 + tid;
    int q = li >> 4, dd = (li & 15) << 2;
    *(float4*)&Qs[q][dd] = *(const float4*)(Q + ((size_t)b * LL + q0 + q) * DD + dd);
  }
  float mx[8];
#pragma unroll
  for (int i = 0; i < 8; ++i) mx[i] = NEG_BIG;
  for (int c = 0; c < LL / 128; ++c) {
    __syncthreads();
#pragma unroll
    for (int it = 0; it < 8; ++it) {
      int li = it * 256 + tid;
      int kk = li >> 4, dd = (li & 15) << 2;
      int gk = idx[c * 128 + kk];
      *(float4*)&Ks[kk][dd] = *(const float4*)(K + ((size_t)b * LL + gk) * DD + dd);
    }
    __syncthreads();
    float acc[8][8];
#pragma unroll
    for (int i = 0; i < 8; ++i)
#pragma unroll
      for (int j = 0; j < 8; ++j) acc[i][j] = 0.f;
#pragma unroll 2
    for (int dd = 0; dd < 64; dd += 4) {
      float4 qf[8];
#pragma unroll
      for (int i = 0; i < 8; ++i) qf[i] = *(const float4*)&Qs[tx + 16 * i][dd];
#pragma unroll
      for (int j = 0; j < 8; ++j) {
        float4 kf = *(const float4*)&Ks[ty + 16 * j][dd];
#pragma unroll
        for (int i = 0; i < 8; ++i)
          acc[i][j] += qf[i].x * kf.x + qf[i].y * kf.y + qf[i].z * kf.z + qf[i].w * kf.w;
      }
    }
#pragma unroll
    for (int i = 0; i < 8; ++i) {
      float m01 = fmaxf(fmaxf(acc[i][0], acc[i][1]), fmaxf(acc[i][2], acc[i][3]));
      float m23 = fmaxf(fmaxf(acc[i][4], acc[i][5]), fmaxf(acc[i][6], acc[i][7]));
      mx[i] = fmaxf(mx[i], fmaxf(m01, m23));
    }
  }
  __syncthreads();
#pragma unroll
  for (int i = 0; i < 8; ++i) red[tx + 16 * i][ty] = mx[i];
  __syncthreads();
  if (tid < 128) {
    float m = red[tid][0];
#pragma unroll
    for (int tt = 1; tt < 16; ++tt) m = fmaxf(m, red[tid][tt]);
    float s = 0.f;
#pragma unroll 16
    for (int d = 0; d < 64; ++d) s += Qs[tid][d] * KsumS[d];
    M[b * LL + q0 + tid] = m - s * (1.0f / (float)LL);
  }
}

__global__ __launch_bounds__(256) void topk_kernel(const float* __restrict__ M,
                                                   int* __restrict__ topi) {
  int b = blockIdx.x, tid = threadIdx.x;
  __shared__ float mv[LL];
  __shared__ float wv[4];
  __shared__ int wi[4];
  for (int j = tid; j < LL; j += 256) mv[j] = M[b * LL + j];
  __syncthreads();
  for (int t = 0; t < UU; ++t) {
    float bv = NEG_BIG;
    int bi = 0x7fffffff;
    for (int j = tid; j < LL; j += 256) {
      float v = mv[j];
      if (v > bv) { bv = v; bi = j; }
    }
#pragma unroll
    for (int off = 32; off > 0; off >>= 1) {
      float ov = __shfl_down(bv, off);
      int oi = __shfl_down(bi, off);
      if (ov > bv || (ov == bv && oi < bi)) { bv = ov; bi = oi; }
    }
    if ((tid & 63) == 0) { wv[tid >> 6] = bv; wi[tid >> 6] = bi; }
    __syncthreads();
    if (tid == 0) {
#pragma unroll
      for (int w = 1; w < 4; ++w)
        if (wv[w] > bv || (wv[w] == bv && wi[w] < bi)) { bv = wv[w]; bi = wi[w]; }
      topi[b * UU + t] = bi;
      mv[bi] = NEG_BIG;
    }
    __syncthreads();
  }
}

// ---------------------------------------------------------------------------
extern "C" void kernel_launch(void* const* d_in, const int* in_sizes, int n_in,
                              void* d_out, int out_size, void* d_ws, size_t ws_size,
                              hipStream_t stream) {
  (void)in_sizes; (void)n_in; (void)out_size;
  const float* Q = (const float*)d_in[0];
  const float* K = (const float*)d_in[1];
  const float* V = (const float*)d_in[2];
  const int* idx = (const int*)d_in[3];

  float* out = (float*)d_out;
  float* scores = out + (size_t)BB * UU * DD;

  // fast-path workspace layout
  const size_t qb_off = 0;
  const size_t kg_off = qb_off + (size_t)BB * LL * DD * sizeof(ushort_t);
  const size_t kpart_off = kg_off + (size_t)BB * LL * DD * sizeof(ushort_t);
  const size_t mb_off = kpart_off + (size_t)BB * 16 * DD * sizeof(float);
  const size_t mpart_off = mb_off + (size_t)BB * LL * sizeof(float);
  const size_t cand_off = mpart_off + (size_t)BB * CC * 8 * sizeof(float);
  const size_t topi_off = cand_off + (size_t)BB * CC * sizeof(int);
  const size_t need = topi_off + (size_t)BB * UU * sizeof(int);

  char* ws = (char*)d_ws;
  if (ws_size >= need) {
    ushort_t* Qb = (ushort_t*)(ws + qb_off);
    ushort_t* Kg = (ushort_t*)(ws + kg_off);
    float* Kpart = (float*)(ws + kpart_off);
    float* Mb = (float*)(ws + mb_off);
    float* Mpart = (float*)(ws + mpart_off);
    int* cand = (int*)(ws + cand_off);
    int* topi = (int*)(ws + topi_off);

    ksum_kernel<<<dim3(16, BB), 256, 0, stream>>>(K, idx, Kpart);
    prep_kernel<<<dim3(16, BB), 256, 0, stream>>>(Q, K, idx, Qb, Kg);
    mfma_m_kernel<<<dim3(LL / 128, BB), 256, 0, stream>>>(Qb, Kg, Q, Kpart, Mb);
    cand_kernel<<<BB, 256, 0, stream>>>(Mb, cand);
    rescue_kernel<<<dim3(8, BB), 256, 0, stream>>>(Q, K, idx, cand, Mpart);
    select_kernel<<<BB, 64, 0, stream>>>(Q, Kpart, cand, Mpart, topi);
    scores_kernel<<<dim3(LL / 256, BB), 256, 0, stream>>>(Q, K, topi, scores);
    softmax_pv_kernel<<<dim3(UU / 4, BB), 256, 0, stream>>>(scores, V, out);
  } else {
    // fp32 fallback (round-2 path), aliasing dead d_out regions
    size_t need2 =
        (size_t)(BB * LL + BB * 16 * DD) * sizeof(float) + (size_t)(BB * UU) * sizeof(int);
    float* M;
    float* Kpart;
    int* topi;
    if (ws_size >= need2) {
      M = (float*)d_ws;
      Kpart = M + BB * LL;
      topi = (int*)(Kpart + BB * 16 * DD);
    } else {
      M = scores;
      Kpart = scores + BB * LL;
      topi = (int*)out;
    }
    ksum_kernel<<<dim3(16, BB), 256, 0, stream>>>(K, idx, Kpart);
    m_kernel<<<dim3(LL / 128, BB), 256, 0, stream>>>(Q, K, idx, Kpart, M);
    topk_kernel<<<BB, 256, 0, stream>>>(M, topi);
    scores_kernel<<<dim3(LL / 256, BB), 256, 0, stream>>>(Q, K, topi, scores);
    softmax_pv_kernel<<<dim3(UU / 4, BB), 256, 0, stream>>>(scores, V, out);
  }
}

// Round 4
// 265.543 us; speedup vs baseline: 3.1004x; 1.5505x over previous
//
#include <hip/hip_runtime.h>
#include <math.h>

#define BB 32
#define LL 2048
#define DD 64
#define UU 40
#define CC 64            // bf16-phase candidates per batch
#define NSEG 8           // epilogue key segments (256 keys each)
#define NEG_BIG (-3.0e38f)

typedef __attribute__((ext_vector_type(8))) short short8;
typedef __attribute__((ext_vector_type(4))) float f32x4;
typedef unsigned long long ull;
typedef unsigned int uint;
typedef unsigned short ushort_t;

__device__ __forceinline__ unsigned short f2bf(float f) {
  uint u = __float_as_uint(f);
  u += 0x7FFFu + ((u >> 16) & 1u);   // RNE
  return (unsigned short)(u >> 16);
}
__device__ __forceinline__ uint fsort(float f) {
  uint u = __float_as_uint(f);
  return (u & 0x80000000u) ? ~u : (u | 0x80000000u);  // monotonic map
}
__device__ __forceinline__ ull shfl_xor_u64(ull x, int m) {
  uint lo = (uint)x, hi = (uint)(x >> 32);
  lo = __shfl_xor(lo, m);
  hi = __shfl_xor(hi, m);
  return ((ull)hi << 32) | lo;
}

// ---------------------------------------------------------------------------
// Kernel 1: fused prep+ksum. Converts Q->bf16 (Qb), gathered K->bf16 (Kg),
// and accumulates partial Ksum (Kpart[b][p][d]) from the same gathered rows.
// ---------------------------------------------------------------------------
__global__ __launch_bounds__(256) void prep_ksum_kernel(const float* __restrict__ Q,
                                                        const float* __restrict__ K,
                                                        const int* __restrict__ idx,
                                                        ushort_t* __restrict__ Qb,
                                                        ushort_t* __restrict__ Kg,
                                                        float* __restrict__ Kpart) {
  int p = blockIdx.x, b = blockIdx.y, t = threadIdx.x;
  int g = t & 7;  // 16B group = 8 elements
  float4 sa = {0.f, 0.f, 0.f, 0.f}, sb = {0.f, 0.f, 0.f, 0.f};
#pragma unroll
  for (int it = 0; it < 4; ++it) {
    int r = p * 128 + it * 32 + (t >> 3);
    {  // Q row r
      const float* src = Q + ((size_t)b * LL + r) * DD + g * 8;
      float4 a = *(const float4*)src;
      float4 c4 = *(const float4*)(src + 4);
      int4 o;
      o.x = (int)(f2bf(a.x) | ((uint)f2bf(a.y) << 16));
      o.y = (int)(f2bf(a.z) | ((uint)f2bf(a.w) << 16));
      o.z = (int)(f2bf(c4.x) | ((uint)f2bf(c4.y) << 16));
      o.w = (int)(f2bf(c4.z) | ((uint)f2bf(c4.w) << 16));
      *(int4*)(Qb + ((size_t)b * LL + r) * DD + g * 8) = o;
    }
    {  // gathered K row r
      int gk = idx[r];
      const float* src = K + ((size_t)b * LL + gk) * DD + g * 8;
      float4 a = *(const float4*)src;
      float4 c4 = *(const float4*)(src + 4);
      sa.x += a.x; sa.y += a.y; sa.z += a.z; sa.w += a.w;
      sb.x += c4.x; sb.y += c4.y; sb.z += c4.z; sb.w += c4.w;
      int4 o;
      o.x = (int)(f2bf(a.x) | ((uint)f2bf(a.y) << 16));
      o.y = (int)(f2bf(a.z) | ((uint)f2bf(a.w) << 16));
      o.z = (int)(f2bf(c4.x) | ((uint)f2bf(c4.y) << 16));
      o.w = (int)(f2bf(c4.z) | ((uint)f2bf(c4.w) << 16));
      *(int4*)(Kg + ((size_t)b * LL + r) * DD + g * 8) = o;
    }
  }
  __shared__ float red[32][64];
  int rt = t >> 3;
  *(float4*)&red[rt][g * 8] = sa;
  *(float4*)&red[rt][g * 8 + 4] = sb;
  __syncthreads();
  if (t < 64) {
    float s = 0.f;
#pragma unroll
    for (int r = 0; r < 32; ++r) s += red[r][t];
    Kpart[(b * 16 + p) * 64 + t] = s;
  }
}

// ---------------------------------------------------------------------------
// Kernel 2: bf16 MFMA M-scores. Mb[b][q] = max_j(Q.K_sample[j]) - (Q.Ksum)/L.
// ---------------------------------------------------------------------------
__global__ __launch_bounds__(256) void mfma_m_kernel(const ushort_t* __restrict__ Qb,
                                                     const ushort_t* __restrict__ Kg,
                                                     const float* __restrict__ Q,
                                                     const float* __restrict__ Kpart,
                                                     float* __restrict__ Mb) {
  __shared__ __align__(16) ushort_t Qs[128 * 64];  // 16 KB, swizzled
  __shared__ __align__(16) ushort_t Ks[128 * 64];  // 16 KB, swizzled
  __shared__ float Mmax[2][128];
  __shared__ float KsumS[64];

  int b = blockIdx.y, q0 = blockIdx.x * 128;
  int t = threadIdx.x;
  int w = t >> 6, L = t & 63;

  if (t < 64) {
    float s = 0.f;
#pragma unroll
    for (int p = 0; p < 16; ++p) s += Kpart[(b * 16 + p) * 64 + t];
    KsumS[t] = s;
  }

  {
    int g = t & 7;
#pragma unroll
    for (int it = 0; it < 4; ++it) {
      int r = it * 32 + (t >> 3);
      int4 v = *(const int4*)(Qb + ((size_t)b * LL + q0 + r) * DD + g * 8);
      *(int4*)&Qs[r * 64 + 8 * (g ^ (r & 7))] = v;
    }
  }

  f32x4 mx[4];
#pragma unroll
  for (int i = 0; i < 4; ++i) mx[i] = (f32x4){NEG_BIG, NEG_BIG, NEG_BIG, NEG_BIG};

  const int waveQ = 64 * (w & 1);
  const int waveK = 64 * (w >> 1);
  const int lm = L & 15;
  const int lq = L >> 4;

  for (int c = 0; c < LL / 128; ++c) {
    __syncthreads();
    {
      int g = t & 7;
#pragma unroll
      for (int it = 0; it < 4; ++it) {
        int r = it * 32 + (t >> 3);
        int4 v = *(const int4*)(Kg + ((size_t)b * LL + c * 128 + r) * DD + g * 8);
        *(int4*)&Ks[r * 64 + 8 * (g ^ (r & 7))] = v;
      }
    }
    __syncthreads();

    f32x4 acc[4][4];
#pragma unroll
    for (int i = 0; i < 4; ++i)
#pragma unroll
      for (int j = 0; j < 4; ++j) acc[i][j] = (f32x4){0.f, 0.f, 0.f, 0.f};

#pragma unroll
    for (int s = 0; s < 2; ++s) {
      int g = 4 * s + lq;
      short8 A[4];
#pragma unroll
      for (int qt = 0; qt < 4; ++qt) {
        int r = waveQ + 16 * qt + lm;
        A[qt] = *(const short8*)&Qs[r * 64 + 8 * (g ^ (r & 7))];
      }
#pragma unroll
      for (int kt = 0; kt < 4; ++kt) {
        int rB = waveK + 16 * kt + lm;
        short8 Bf = *(const short8*)&Ks[rB * 64 + 8 * (g ^ (rB & 7))];
#pragma unroll
        for (int qt = 0; qt < 4; ++qt) {
          acc[qt][kt] = __builtin_amdgcn_mfma_f32_16x16x32_bf16(A[qt], Bf, acc[qt][kt], 0, 0, 0);
        }
      }
    }
#pragma unroll
    for (int qt = 0; qt < 4; ++qt)
#pragma unroll
      for (int kt = 0; kt < 4; ++kt) {
#pragma unroll
        for (int r4 = 0; r4 < 4; ++r4) mx[qt][r4] = fmaxf(mx[qt][r4], acc[qt][kt][r4]);
      }
  }

#pragma unroll
  for (int qt = 0; qt < 4; ++qt) {
#pragma unroll
    for (int r4 = 0; r4 < 4; ++r4) {
      float v = mx[qt][r4];
      v = fmaxf(v, __shfl_xor(v, 1));
      v = fmaxf(v, __shfl_xor(v, 2));
      v = fmaxf(v, __shfl_xor(v, 4));
      v = fmaxf(v, __shfl_xor(v, 8));
      mx[qt][r4] = v;
    }
  }
  if (lm < 4) {
    int qt = lm;
#pragma unroll
    for (int r4 = 0; r4 < 4; ++r4) {
      Mmax[w >> 1][waveQ + 16 * qt + 4 * lq + r4] = mx[qt][r4];
    }
  }
  __syncthreads();

  if (t < 128) {
    float m = fmaxf(Mmax[0][t], Mmax[1][t]);
    const float4* Qr = (const float4*)(Q + ((size_t)b * LL + q0 + t) * DD);
    float s = 0.f;
#pragma unroll
    for (int i = 0; i < 16; ++i) {
      float4 qv = Qr[i];
      s += qv.x * KsumS[4 * i] + qv.y * KsumS[4 * i + 1] + qv.z * KsumS[4 * i + 2] +
           qv.w * KsumS[4 * i + 3];
    }
    Mb[b * LL + q0 + t] = m - s * (1.0f / (float)LL);
  }
}

// ---------------------------------------------------------------------------
// Kernel 3: per-batch top-64 candidate set by Mb (set only; any order).
// ---------------------------------------------------------------------------
__global__ __launch_bounds__(256) void cand_kernel(const float* __restrict__ Mb,
                                                   int* __restrict__ cand) {
  int b = blockIdx.x, t = threadIdx.x;
  int w = t >> 6;
  float v[8];
#pragma unroll
  for (int i = 0; i < 8; ++i) v[i] = Mb[b * LL + t + 256 * i];
  __shared__ ull warr[4];
  __shared__ ull winls;
  for (int round = 0; round < CC; ++round) {
    float bv = v[0];
    int bi = 0;
#pragma unroll
    for (int i = 1; i < 8; ++i)
      if (v[i] > bv) { bv = v[i]; bi = i; }
    ull key = ((ull)fsort(bv) << 32) | (ull)(uint)(t + 256 * bi);
#pragma unroll
    for (int m = 1; m < 64; m <<= 1) {
      ull o = shfl_xor_u64(key, m);
      if (o > key) key = o;
    }
    if ((t & 63) == 0) warr[w] = key;
    __syncthreads();
    if (t == 0) {
      ull k = warr[0];
#pragma unroll
      for (int i = 1; i < 4; ++i)
        if (warr[i] > k) k = warr[i];
      winls = k;
      cand[b * CC + round] = (int)(k & 0xFFFFFFFFull);
    }
    __syncthreads();
    int wj = (int)(winls & 0xFFFFFFFFull);
    if (t == (wj & 255)) v[wj >> 8] = NEG_BIG;
  }
}

// ---------------------------------------------------------------------------
// Kernel 4: fp32 rescue partial maxes over candidate queries.
// ---------------------------------------------------------------------------
__global__ __launch_bounds__(256) void rescue_kernel(const float* __restrict__ Q,
                                                     const float* __restrict__ K,
                                                     const int* __restrict__ idx,
                                                     const int* __restrict__ cand,
                                                     float* __restrict__ Mpart) {
  int seg = blockIdx.x, b = blockIdx.y, t = threadIdx.x;
  int w = t >> 6;
  __shared__ int cidx[CC];
  __shared__ float Qc[CC][DD];
  __shared__ float redm[CC][4];
  if (t < CC) cidx[t] = cand[b * CC + t];
  __syncthreads();
  for (int li = t; li < CC * 16; li += 256) {
    int row = li >> 4, g4 = li & 15;
    *(float4*)&Qc[row][4 * g4] =
        *(const float4*)(Q + ((size_t)b * LL + cidx[row]) * DD + 4 * g4);
  }
  __syncthreads();

  int key = idx[seg * 256 + t];
  float4 kr[16];
  const float4* Krow = (const float4*)(K + ((size_t)b * LL + key) * DD);
#pragma unroll
  for (int i = 0; i < 16; ++i) kr[i] = Krow[i];

#pragma unroll 2
  for (int u = 0; u < CC; ++u) {
    const float4* qp = (const float4*)&Qc[u][0];
    float d = 0.f;
#pragma unroll
    for (int i = 0; i < 16; ++i) {
      float4 qv = qp[i];
      d = fmaf(qv.x, kr[i].x, d);
      d = fmaf(qv.y, kr[i].y, d);
      d = fmaf(qv.z, kr[i].z, d);
      d = fmaf(qv.w, kr[i].w, d);
    }
#pragma unroll
    for (int m = 1; m < 64; m <<= 1) d = fmaxf(d, __shfl_xor(d, m));
    if ((t & 63) == 0) redm[u][w] = d;
  }
  __syncthreads();
  if (t < CC) {
    float m = fmaxf(fmaxf(redm[t][0], redm[t][1]), fmaxf(redm[t][2], redm[t][3]));
    Mpart[((size_t)b * CC + t) * 8 + seg] = m;
  }
}

// ---------------------------------------------------------------------------
// Kernel 5: exact fp32 M for candidates; exact top-40 with lax.top_k ties.
// ---------------------------------------------------------------------------
__global__ __launch_bounds__(64) void select_kernel(const float* __restrict__ Q,
                                                    const float* __restrict__ Kpart,
                                                    const int* __restrict__ cand,
                                                    const float* __restrict__ Mpart,
                                                    int* __restrict__ topi) {
  int b = blockIdx.x, t = threadIdx.x;
  __shared__ float KsumS[64];
  {
    float s = 0.f;
#pragma unroll
    for (int p = 0; p < 16; ++p) s += Kpart[(b * 16 + p) * 64 + t];
    KsumS[t] = s;
  }
  __syncthreads();
  int ci = cand[b * CC + t];
  float m = NEG_BIG;
#pragma unroll
  for (int s = 0; s < 8; ++s) m = fmaxf(m, Mpart[((size_t)b * CC + t) * 8 + s]);
  const float4* Qr = (const float4*)(Q + ((size_t)b * LL + ci) * DD);
  float s = 0.f;
#pragma unroll
  for (int i = 0; i < 16; ++i) {
    float4 qv = Qr[i];
    s += qv.x * KsumS[4 * i] + qv.y * KsumS[4 * i + 1] + qv.z * KsumS[4 * i + 2] +
         qv.w * KsumS[4 * i + 3];
  }
  float Mf = m - s * (1.0f / (float)LL);
  ull key = ((ull)fsort(Mf) << 32) | (ull)(uint)(2047 - ci);
  for (int round = 0; round < UU; ++round) {
    ull k = key;
#pragma unroll
    for (int mk = 1; mk < 64; mk <<= 1) {
      ull o = shfl_xor_u64(k, mk);
      if (o > k) k = o;
    }
    int wci = 2047 - (int)(k & 0xFFFFFFFFull);
    if (t == 0) topi[b * UU + round] = wci;
    if (ci == wci) key = 0;
  }
}

// ---------------------------------------------------------------------------
// Kernel 6: FUSED epilogue per (seg, b): scores (exact output) + exp (no max
// subtraction: |s|<~6 so exp<=~400, safe in fp32; softmax shift-invariant) +
// per-seg exp-sum + partial P.V with float4 V loads.
//   Opart[b][seg][u][d] (unnormalized), lpart[b][seg][u].
// ---------------------------------------------------------------------------
__global__ __launch_bounds__(256, 1) void fused_epilogue_kernel(
    const float* __restrict__ Q, const float* __restrict__ K,
    const float* __restrict__ V, const int* __restrict__ topi,
    float* __restrict__ scores, float* __restrict__ Opart,
    float* __restrict__ lpart) {
  int seg = blockIdx.x, b = blockIdx.y, t = threadIdx.x;
  __shared__ int cidx[UU];
  __shared__ float Qc[UU][DD];       // 10240 B
  __shared__ float pT[256 * 41];     // 41984 B; reused as red[4][40][64]
  __shared__ float lw[4][UU];        // 640 B

  if (t < UU) cidx[t] = topi[b * UU + t];
  __syncthreads();
  for (int li = t; li < UU * 16; li += 256) {
    int u = li >> 4, g4 = li & 15;
    *(float4*)&Qc[u][4 * g4] =
        *(const float4*)(Q + ((size_t)b * LL + cidx[u]) * DD + 4 * g4);
  }
  __syncthreads();

  // ---- Phase A: scores + exp (thread t owns key k) ----
  int k = seg * 256 + t;
  float4 kr[16];
  const float4* Krow = (const float4*)(K + ((size_t)b * LL + k) * DD);
#pragma unroll
  for (int i = 0; i < 16; ++i) kr[i] = Krow[i];

  float p[UU];
#pragma unroll
  for (int u = 0; u < UU; ++u) {
    const float4* qp = (const float4*)&Qc[u][0];
    float s = 0.f;
#pragma unroll
    for (int i = 0; i < 16; ++i) {
      float4 qv = qp[i];
      s += qv.x * kr[i].x + qv.y * kr[i].y + qv.z * kr[i].z + qv.w * kr[i].w;
    }
    s *= 0.125f;
    scores[((size_t)(b * UU + u)) * LL + k] = s;
    p[u] = __expf(s);
  }

  // ---- Phase B: per-seg exp-sums (wave shuffle + LDS) + transpose p ----
  int w = t >> 6;
#pragma unroll
  for (int u = 0; u < UU; ++u) {
    float ls = p[u];
#pragma unroll
    for (int off = 32; off > 0; off >>= 1) ls += __shfl_xor(ls, off);
    if ((t & 63) == 0) lw[w][u] = ls;
  }
#pragma unroll
  for (int u = 0; u < UU; ++u) pT[t * 41 + u] = p[u];
  __syncthreads();
  if (t < UU) lpart[(size_t)(b * NSEG + seg) * UU + t] =
      lw[0][t] + lw[1][t] + lw[2][t] + lw[3][t];

  // ---- Phase C: partial P.V ----
  // thread (d4 = t&15, c = t>>4): u-group ug = c&3 (10 u), k-quarter kq = c>>2.
  int d4 = t & 15, c = t >> 4;
  int ug = c & 3, kq = c >> 2;
  int u0 = ug * 10;
  float4 acc[10];
#pragma unroll
  for (int j = 0; j < 10; ++j) acc[j] = (float4){0.f, 0.f, 0.f, 0.f};
  const float* Vb = V + ((size_t)b * LL + seg * 256 + kq * 64) * DD;
  for (int kk = 0; kk < 64; ++kk) {
    float4 v4 = *(const float4*)(Vb + (size_t)kk * DD + 4 * d4);
    const float* prow = &pT[(kq * 64 + kk) * 41 + u0];
#pragma unroll
    for (int j = 0; j < 10; ++j) {
      float pj = prow[j];
      acc[j].x += pj * v4.x; acc[j].y += pj * v4.y;
      acc[j].z += pj * v4.z; acc[j].w += pj * v4.w;
    }
  }
  __syncthreads();  // all pT reads done before aliasing as red
  float* red = pT;  // red[kq][u][d] = red[(kq*40+u)*64 + d], 40960 B
#pragma unroll
  for (int j = 0; j < 10; ++j)
    *(float4*)&red[(kq * 40 + u0 + j) * 64 + 4 * d4] = acc[j];
  __syncthreads();
  for (int li = t; li < UU * DD; li += 256) {
    int u = li >> 6, d = li & 63;
    float s = red[(0 * 40 + u) * 64 + d] + red[(1 * 40 + u) * 64 + d] +
              red[(2 * 40 + u) * 64 + d] + red[(3 * 40 + u) * 64 + d];
    Opart[((size_t)(b * NSEG + seg) * UU + u) * DD + d] = s;
  }
}

// ---------------------------------------------------------------------------
// Kernel 7: combine segments: out = (sum_s Opart) / (sum_s lpart).
// ---------------------------------------------------------------------------
__global__ __launch_bounds__(256) void combine_kernel(const float* __restrict__ Opart,
                                                      const float* __restrict__ lpart,
                                                      float* __restrict__ out) {
  int b = blockIdx.x, t = threadIdx.x;
  __shared__ float Linv[UU];
  if (t < UU) {
    float Lsum = 0.f;
#pragma unroll
    for (int s = 0; s < NSEG; ++s) Lsum += lpart[(size_t)(b * NSEG + s) * UU + t];
    Linv[t] = 1.0f / Lsum;
  }
  __syncthreads();
  for (int li = t; li < UU * DD; li += 256) {
    int u = li >> 6, d = li & 63;
    float O = 0.f;
#pragma unroll
    for (int s = 0; s < NSEG; ++s)
      O += Opart[((size_t)(b * NSEG + s) * UU + u) * DD + d];
    out[((size_t)b * UU + u) * DD + d] = O * Linv[u];
  }
}

// ========================= fp32 fallback (round-2 path) ====================
__global__ __launch_bounds__(256) void ksum_kernel(const float* __restrict__ K,
                                                   const int* __restrict__ idx,
                                                   float* __restrict__ Kpart) {
  int p = blockIdx.x, b = blockIdx.y, tid = threadIdx.x;
  int d = tid & 63, c = tid >> 6;
  const float* Kb = K + (size_t)b * LL * DD;
  float acc = 0.f;
  int j0 = p * 128 + c * 32;
#pragma unroll 4
  for (int t = 0; t < 32; ++t) acc += Kb[(size_t)idx[j0 + t] * DD + d];
  __shared__ float red[256];
  red[tid] = acc;
  __syncthreads();
  if (c == 0) Kpart[(b * 16 + p) * 64 + d] = red[d] + red[64 + d] + red[128 + d] + red[192 + d];
}

__global__ __launch_bounds__(256) void m_kernel(const float* __restrict__ Q,
                                                const float* __restrict__ K,
                                                const int* __restrict__ idx,
                                                const float* __restrict__ Kpart,
                                                float* __restrict__ M) {
  __shared__ float Qs[128][68];
  __shared__ float Ks[128][68];
  __shared__ float KsumS[64];
  __shared__ float red[128][17];
  int b = blockIdx.y, q0 = blockIdx.x * 128, tid = threadIdx.x;
  int tx = tid & 15, ty = tid >> 4;
  if (tid < 64) {
    float s = 0.f;
#pragma unroll
    for (int p = 0; p < 16; ++p) s += Kpart[(b * 16 + p) * 64 + tid];
    KsumS[tid] = s;
  }
#pragma unroll
  for (int it = 0; it < 8; ++it) {
    int li = it * 256 + tid;
    int q = li >> 4, dd = (li & 15) << 2;
    *(float4*)&Qs[q][dd] = *(const float4*)(Q + ((size_t)b * LL + q0 + q) * DD + dd);
  }
  float mx[8];
#pragma unroll
  for (int i = 0; i < 8; ++i) mx[i] = NEG_BIG;
  for (int c = 0; c < LL / 128; ++c) {
    __syncthreads();
#pragma unroll
    for (int it = 0; it < 8; ++it) {
      int li = it * 256 + tid;
      int kk = li >> 4, dd = (li & 15) << 2;
      int gk = idx[c * 128 + kk];
      *(float4*)&Ks[kk][dd] = *(const float4*)(K + ((size_t)b * LL + gk) * DD + dd);
    }
    __syncthreads();
    float acc[8][8];
#pragma unroll
    for (int i = 0; i < 8; ++i)
#pragma unroll
      for (int j = 0; j < 8; ++j) acc[i][j] = 0.f;
#pragma unroll 2
    for (int dd = 0; dd < 64; dd += 4) {
      float4 qf[8];
#pragma unroll
      for (int i = 0; i < 8; ++i) qf[i] = *(const float4*)&Qs[tx + 16 * i][dd];
#pragma unroll
      for (int j = 0; j < 8; ++j) {
        float4 kf = *(const float4*)&Ks[ty + 16 * j][dd];
#pragma unroll
        for (int i = 0; i < 8; ++i)
          acc[i][j] += qf[i].x * kf.x + qf[i].y * kf.y + qf[i].z * kf.z + qf[i].w * kf.w;
      }
    }
#pragma unroll
    for (int i = 0; i < 8; ++i) {
      float m01 = fmaxf(fmaxf(acc[i][0], acc[i][1]), fmaxf(acc[i][2], acc[i][3]));
      float m23 = fmaxf(fmaxf(acc[i][4], acc[i][5]), fmaxf(acc[i][6], acc[i][7]));
      mx[i] = fmaxf(mx[i], fmaxf(m01, m23));
    }
  }
  __syncthreads();
#pragma unroll
  for (int i = 0; i < 8; ++i) red[tx + 16 * i][ty] = mx[i];
  __syncthreads();
  if (tid < 128) {
    float m = red[tid][0];
#pragma unroll
    for (int tt = 1; tt < 16; ++tt) m = fmaxf(m, red[tid][tt]);
    float s = 0.f;
#pragma unroll 16
    for (int d = 0; d < 64; ++d) s += Qs[tid][d] * KsumS[d];
    M[b * LL + q0 + tid] = m - s * (1.0f / (float)LL);
  }
}

__global__ __launch_bounds__(256) void topk_kernel(const float* __restrict__ M,
                                                   int* __restrict__ topi) {
  int b = blockIdx.x, tid = threadIdx.x;
  __shared__ float mv[LL];
  __shared__ float wv[4];
  __shared__ int wi[4];
  for (int j = tid; j < LL; j += 256) mv[j] = M[b * LL + j];
  __syncthreads();
  for (int t = 0; t < UU; ++t) {
    float bv = NEG_BIG;
    int bi = 0x7fffffff;
    for (int j = tid; j < LL; j += 256) {
      float v = mv[j];
      if (v > bv) { bv = v; bi = j; }
    }
#pragma unroll
    for (int off = 32; off > 0; off >>= 1) {
      float ov = __shfl_down(bv, off);
      int oi = __shfl_down(bi, off);
      if (ov > bv || (ov == bv && oi < bi)) { bv = ov; bi = oi; }
    }
    if ((tid & 63) == 0) { wv[tid >> 6] = bv; wi[tid >> 6] = bi; }
    __syncthreads();
    if (tid == 0) {
#pragma unroll
      for (int w = 1; w < 4; ++w)
        if (wv[w] > bv || (wv[w] == bv && wi[w] < bi)) { bv = wv[w]; bi = wi[w]; }
      topi[b * UU + t] = bi;
      mv[bi] = NEG_BIG;
    }
    __syncthreads();
  }
}

__global__ __launch_bounds__(256) void scores_kernel(const float* __restrict__ Q,
                                                     const float* __restrict__ K,
                                                     const int* __restrict__ topi,
                                                     float* __restrict__ scores) {
  int b = blockIdx.y;
  int k = blockIdx.x * 256 + threadIdx.x;
  __shared__ float Qr[UU][DD];
  for (int li = threadIdx.x; li < UU * DD; li += 256) {
    int u = li >> 6, d = li & 63;
    Qr[u][d] = Q[((size_t)b * LL + topi[b * UU + u]) * DD + d];
  }
  __syncthreads();
  float4 kr[16];
  const float4* Krow = (const float4*)(K + ((size_t)b * LL + k) * DD);
#pragma unroll
  for (int i = 0; i < 16; ++i) kr[i] = Krow[i];
  for (int u = 0; u < UU; ++u) {
    float s = 0.f;
#pragma unroll
    for (int i = 0; i < 16; ++i) {
      float4 qv = *(const float4*)&Qr[u][i << 2];
      s += qv.x * kr[i].x + qv.y * kr[i].y + qv.z * kr[i].z + qv.w * kr[i].w;
    }
    scores[((size_t)(b * UU + u)) * LL + k] = s * 0.125f;
  }
}

__global__ __launch_bounds__(256) void softmax_pv_kernel(const float* __restrict__ scores,
                                                         const float* __restrict__ V,
                                                         float* __restrict__ out) {
  int b = blockIdx.y;
  int u0 = blockIdx.x * 4;
  int tid = threadIdx.x;
  __shared__ float p[4][LL];
  __shared__ float wred[4];
  __shared__ float inv_s[4];
  __shared__ float r2[256];
#pragma unroll
  for (int uu = 0; uu < 4; ++uu) {
    const float* srow = scores + ((size_t)(b * UU + u0 + uu)) * LL;
    float m = NEG_BIG;
    for (int j = tid; j < LL; j += 256) m = fmaxf(m, srow[j]);
#pragma unroll
    for (int off = 32; off > 0; off >>= 1) m = fmaxf(m, __shfl_down(m, off));
    if ((tid & 63) == 0) wred[tid >> 6] = m;
    __syncthreads();
    float smax = fmaxf(fmaxf(wred[0], wred[1]), fmaxf(wred[2], wred[3]));
    __syncthreads();
    float ls = 0.f;
    for (int j = tid; j < LL; j += 256) {
      float e = __expf(srow[j] - smax);
      p[uu][j] = e;
      ls += e;
    }
#pragma unroll
    for (int off = 32; off > 0; off >>= 1) ls += __shfl_down(ls, off);
    if ((tid & 63) == 0) wred[tid >> 6] = ls;
    __syncthreads();
    if (tid == 0) inv_s[uu] = 1.0f / (wred[0] + wred[1] + wred[2] + wred[3]);
    __syncthreads();
  }
  int d = tid & 63, c = tid >> 6;
  float acc[4] = {0.f, 0.f, 0.f, 0.f};
  const float* Vb = V + (size_t)b * LL * DD;
  int k0 = c * (LL / 4), k1 = k0 + (LL / 4);
  for (int k = k0; k < k1; ++k) {
    float v = Vb[(size_t)k * DD + d];
#pragma unroll
    for (int uu = 0; uu < 4; ++uu) acc[uu] += p[uu][k] * v;
  }
#pragma unroll
  for (int uu = 0; uu < 4; ++uu) {
    r2[tid] = acc[uu];
    __syncthreads();
    if (c == 0) {
      out[((size_t)(b * UU) + u0 + uu) * DD + d] =
          (r2[d] + r2[64 + d] + r2[128 + d] + r2[192 + d]) * inv_s[uu];
    }
    __syncthreads();
  }
}

// ---------------------------------------------------------------------------
extern "C" void kernel_launch(void* const* d_in, const int* in_sizes, int n_in,
                              void* d_out, int out_size, void* d_ws, size_t ws_size,
                              hipStream_t stream) {
  (void)in_sizes; (void)n_in; (void)out_size;
  const float* Q = (const float*)d_in[0];
  const float* K = (const float*)d_in[1];
  const float* V = (const float*)d_in[2];
  const int* idx = (const int*)d_in[3];

  float* out = (float*)d_out;
  float* scores = out + (size_t)BB * UU * DD;

  // fast-path workspace layout (same footprint as round 3)
  const size_t qb_off = 0;
  const size_t kg_off = qb_off + (size_t)BB * LL * DD * sizeof(ushort_t);
  const size_t kpart_off = kg_off + (size_t)BB * LL * DD * sizeof(ushort_t);
  const size_t mb_off = kpart_off + (size_t)BB * 16 * DD * sizeof(float);
  const size_t mpart_off = mb_off + (size_t)BB * LL * sizeof(float);
  const size_t cand_off = mpart_off + (size_t)BB * CC * 8 * sizeof(float);
  const size_t topi_off = cand_off + (size_t)BB * CC * sizeof(int);
  const size_t need = topi_off + (size_t)BB * UU * sizeof(int);

  char* ws = (char*)d_ws;
  if (ws_size >= need) {
    ushort_t* Qb = (ushort_t*)(ws + qb_off);
    ushort_t* Kg = (ushort_t*)(ws + kg_off);
    float* Kpart = (float*)(ws + kpart_off);
    float* Mb = (float*)(ws + mb_off);
    float* Mpart = (float*)(ws + mpart_off);
    int* cand = (int*)(ws + cand_off);
    int* topi = (int*)(ws + topi_off);
    // Opart/lpart alias the Qb/Kg region — dead after mfma_m_kernel.
    float* Opart = (float*)(ws + qb_off);  // BB*NSEG*UU*DD floats = 2.62 MB
    float* lpart = Opart + (size_t)BB * NSEG * UU * DD;  // BB*NSEG*UU floats

    prep_ksum_kernel<<<dim3(16, BB), 256, 0, stream>>>(Q, K, idx, Qb, Kg, Kpart);
    mfma_m_kernel<<<dim3(LL / 128, BB), 256, 0, stream>>>(Qb, Kg, Q, Kpart, Mb);
    cand_kernel<<<BB, 256, 0, stream>>>(Mb, cand);
    rescue_kernel<<<dim3(8, BB), 256, 0, stream>>>(Q, K, idx, cand, Mpart);
    select_kernel<<<BB, 64, 0, stream>>>(Q, Kpart, cand, Mpart, topi);
    fused_epilogue_kernel<<<dim3(NSEG, BB), 256, 0, stream>>>(Q, K, V, topi, scores,
                                                              Opart, lpart);
    combine_kernel<<<BB, 256, 0, stream>>>(Opart, lpart, out);
  } else {
    // fp32 fallback (round-2 path), aliasing dead d_out regions
    size_t need2 =
        (size_t)(BB * LL + BB * 16 * DD) * sizeof(float) + (size_t)(BB * UU) * sizeof(int);
    float* M;
    float* Kpart;
    int* topi;
    if (ws_size >= need2) {
      M = (float*)d_ws;
      Kpart = M + BB * LL;
      topi = (int*)(Kpart + BB * 16 * DD);
    } else {
      M = scores;
      Kpart = scores + BB * LL;
      topi = (int*)out;
    }
    ksum_kernel<<<dim3(16, BB), 256, 0, stream>>>(K, idx, Kpart);
    m_kernel<<<dim3(LL / 128, BB), 256, 0, stream>>>(Q, K, idx, Kpart, M);
    topk_kernel<<<BB, 256, 0, stream>>>(M, topi);
    scores_kernel<<<dim3(LL / 256, BB), 256, 0, stream>>>(Q, K, topi, scores);
    softmax_pv_kernel<<<dim3(UU / 4, BB), 256, 0, stream>>>(scores, V, out);
  }
}